// Round 4
// baseline (2629.563 us; speedup 1.0000x reference)
//
#include <hip/hip_runtime.h>
#include <cstdint>

// AttentionDecoder: B=128, L=196, T_dec=31, E=H=F=A=512, V=10000
// Out: logits (128*31*10000) | alphas (128*31*196) | dec_len (128), fp32.
//
// Structure: emb contributions precomputed for all steps (teacher forcing);
// pre GEMM deferred/batched; per-step chain = score -> ctx -> gates -> tail.

#define DEV __device__ __forceinline__

typedef __bf16 bf16x8 __attribute__((ext_vector_type(8)));
typedef float  f32x4  __attribute__((ext_vector_type(4)));

DEV float sigmf(float v) { return 1.f / (1.f + expf(-v)); }

DEV ushort f2bf(float f) {
  union { float f; uint32_t u; } c; c.f = f;
  uint32_t u = c.u;
  return (ushort)((u + 0x7FFFu + ((u >> 16) & 1u)) >> 16);
}
DEV float bf2f(ushort h) {
  union { uint32_t u; float f; } c; c.u = ((uint32_t)h) << 16;
  return c.f;
}
DEV void cvt8(const float* __restrict__ s, ushort* __restrict__ d) {
  float4 a = *(const float4*)s;
  float4 b = *(const float4*)(s + 4);
  *(ushort4*)d = make_ushort4(f2bf(a.x), f2bf(a.y), f2bf(a.z), f2bf(a.w));
  *(ushort4*)(d + 4) = make_ushort4(f2bf(b.x), f2bf(b.y), f2bf(b.z), f2bf(b.w));
}

// ---------------------------------------------------------------------------
// 128x128-tile bf16 MFMA GEMM tile body (256 thr = 4 waves, 64x64/wave).
// mode 0: fp32 out (+bias if non-null); 1: bf16 out; 2: bf16 out tanh.
DEV void mfma_body(ushort* As, ushort* Ws, int mt, int nt,
                   const ushort* __restrict__ A, int lda,
                   const ushort* __restrict__ W, int ldw,
                   int K, int mode, const float* __restrict__ bias,
                   float* __restrict__ Cf, ushort* __restrict__ Cb, int ldc)
{
  const int tid = threadIdx.x;
  const int m0 = mt * 128, n0 = nt * 128;
  const int wv = tid >> 6, lane = tid & 63;
  const int rw = (wv & 1) * 64, cw = (wv >> 1) * 64;
  const int lrow = lane & 15, lk = (lane >> 4) * 8;
  f32x4 acc[4][4];
#pragma unroll
  for (int i = 0; i < 4; ++i)
#pragma unroll
    for (int j = 0; j < 4; ++j) acc[i][j] = (f32x4){0.f, 0.f, 0.f, 0.f};

  const int srow = tid >> 3;
  const int sc8  = tid & 7;
  for (int k0 = 0; k0 < K; k0 += 64) {
    __syncthreads();
#pragma unroll
    for (int it = 0; it < 4; ++it) {
      int row = it * 32 + srow;
      *(uint4*)&As[row * 72 + sc8 * 8] =
          *(const uint4*)&A[(size_t)(m0 + row) * lda + k0 + sc8 * 8];
      *(uint4*)&Ws[row * 72 + sc8 * 8] =
          *(const uint4*)&W[(size_t)(n0 + row) * ldw + k0 + sc8 * 8];
    }
    __syncthreads();
#pragma unroll
    for (int ks = 0; ks < 64; ks += 32) {
      bf16x8 af[4], bfr[4];
#pragma unroll
      for (int i = 0; i < 4; ++i)
        af[i] = *(const bf16x8*)&As[(rw + i * 16 + lrow) * 72 + ks + lk];
#pragma unroll
      for (int j = 0; j < 4; ++j)
        bfr[j] = *(const bf16x8*)&Ws[(cw + j * 16 + lrow) * 72 + ks + lk];
#pragma unroll
      for (int i = 0; i < 4; ++i)
#pragma unroll
        for (int j = 0; j < 4; ++j)
          acc[i][j] = __builtin_amdgcn_mfma_f32_16x16x32_bf16(af[i], bfr[j],
                                                              acc[i][j], 0, 0, 0);
    }
  }
  const int rsub = (lane >> 4) * 4;
#pragma unroll
  for (int i = 0; i < 4; ++i) {
#pragma unroll
    for (int j = 0; j < 4; ++j) {
      int col = n0 + cw + j * 16 + lrow;
#pragma unroll
      for (int r = 0; r < 4; ++r) {
        int row = m0 + rw + i * 16 + rsub + r;
        float v = acc[i][j][r];
        if (mode == 0)      Cf[(size_t)row * ldc + col] = bias ? v + bias[col] : v;
        else if (mode == 1) Cb[(size_t)row * ldc + col] = f2bf(v);
        else                Cb[(size_t)row * ldc + col] = f2bf(tanhf(v));
      }
    }
  }
}

__global__ __launch_bounds__(256) void k_mfma(
    const ushort* __restrict__ A, int lda, const ushort* __restrict__ W, int ldw,
    int K, int mode, const float* __restrict__ bias,
    float* __restrict__ Cf, ushort* __restrict__ Cb, int ldc)
{
  __shared__ ushort As[128 * 72];
  __shared__ ushort Ws[128 * 72];
  mfma_body(As, Ws, blockIdx.y, blockIdx.x, A, lda, W, ldw, K, mode, bias,
            Cf, Cb, ldc);
}

// ---------------------------------------------------------------------------
// Logits GEMM with XCD-localizing swizzle + LDS-staged coalesced epilogue.
__global__ __launch_bounds__(256) void k_logits(
    const ushort* __restrict__ preA, const ushort* __restrict__ Wo,
    const float* __restrict__ b_out, float* __restrict__ out_logits,
    const int* __restrict__ declen)
{
  __shared__ ushort SMEM[2 * 128 * 72];
  ushort* As = SMEM;
  ushort* Ws = SMEM + 128 * 72;
  int id = blockIdx.x;
  int x = id & 7, g = id >> 3;
  int G = g / 31, row_t = g - G * 31;
  int colt = G * 8 + x;
  if (colt >= 79) return;
  const int tid = threadIdx.x;
  const int m0 = row_t * 128, n0 = colt * 128;
  const int wv = tid >> 6, lane = tid & 63;
  const int rw = (wv & 1) * 64, cw = (wv >> 1) * 64;
  const int lrow = lane & 15, lk = (lane >> 4) * 8;
  f32x4 acc[4][4];
#pragma unroll
  for (int i = 0; i < 4; ++i)
#pragma unroll
    for (int j = 0; j < 4; ++j) acc[i][j] = (f32x4){0.f, 0.f, 0.f, 0.f};
  const int srow = tid >> 3, sc8 = tid & 7;
  for (int k0 = 0; k0 < 512; k0 += 64) {
    __syncthreads();
#pragma unroll
    for (int it = 0; it < 4; ++it) {
      int row = it * 32 + srow;
      *(uint4*)&As[row * 72 + sc8 * 8] =
          *(const uint4*)&preA[(size_t)(m0 + row) * 512 + k0 + sc8 * 8];
      *(uint4*)&Ws[row * 72 + sc8 * 8] =
          *(const uint4*)&Wo[(size_t)(n0 + row) * 512 + k0 + sc8 * 8];
    }
    __syncthreads();
#pragma unroll
    for (int ks = 0; ks < 64; ks += 32) {
      bf16x8 af[4], bfr[4];
#pragma unroll
      for (int i = 0; i < 4; ++i)
        af[i] = *(const bf16x8*)&As[(rw + i * 16 + lrow) * 72 + ks + lk];
#pragma unroll
      for (int j = 0; j < 4; ++j)
        bfr[j] = *(const bf16x8*)&Ws[(cw + j * 16 + lrow) * 72 + ks + lk];
#pragma unroll
      for (int i = 0; i < 4; ++i)
#pragma unroll
        for (int j = 0; j < 4; ++j)
          acc[i][j] = __builtin_amdgcn_mfma_f32_16x16x32_bf16(af[i], bfr[j],
                                                              acc[i][j], 0, 0, 0);
    }
  }
  // epilogue: stage 64x128 fp32 half-tiles in LDS, write coalesced float4 rows
  float* sC = (float*)SMEM;   // 64*132 floats = 33.8 KB <= 36.8 KB
  const int rsub = (lane >> 4) * 4;
  for (int rh = 0; rh < 2; ++rh) {
    __syncthreads();
    if ((wv & 1) == rh) {
#pragma unroll
      for (int i = 0; i < 4; ++i)
#pragma unroll
        for (int j = 0; j < 4; ++j)
#pragma unroll
          for (int r = 0; r < 4; ++r)
            sC[(i * 16 + rsub + r) * 132 + cw + j * 16 + lrow] = acc[i][j][r];
    }
    __syncthreads();
    for (int q = tid; q < 2048; q += 256) {
      int r = q >> 5, qc = q & 31;
      int grow = m0 + rh * 64 + r;          // = t*128 + b
      int tt = grow >> 7, bb = grow & 127;
      bool act = tt < declen[bb];
      int c0 = n0 + qc * 4;
      float4 v = *(float4*)&sC[r * 132 + qc * 4];
      if (act) {
        v.x += b_out[c0]; v.y += b_out[c0 + 1];
        v.z += b_out[c0 + 2]; v.w += b_out[c0 + 3];
      } else v = make_float4(0.f, 0.f, 0.f, 0.f);
      float* dst = out_logits + ((size_t)bb * 31 + tt) * 10000 + c0;
      if (c0 + 3 < 10000) *(float4*)dst = v;
      else {
        const float vv[4] = {v.x, v.y, v.z, v.w};
        for (int k = 0; k < 4; ++k) if (c0 + k < 10000) dst[k] = vv[k];
      }
    }
  }
}

// ---------------------------------------------------------------------------
// Gates GEMM: 32 blocks = 16 N-tiles x 2 parts (part0 gctx, part1 h_prev).
__global__ __launch_bounds__(256) void k_gates(
    const ushort* __restrict__ xAll, const ushort* __restrict__ WgR,
    float* __restrict__ gP, int slot_cur, int slot_prev)
{
  __shared__ ushort As[128 * 72];
  __shared__ ushort Ws[128 * 72];
  int part = blockIdx.x >> 4, nt = blockIdx.x & 15;
  const ushort* A = xAll + (size_t)(part == 0 ? slot_cur : slot_prev) * 196608
                         + (part == 0 ? 512 : 1024);
  mfma_body(As, Ws, 0, nt, A, 1536, WgR + part * 512, 1024, 512, 0,
            nullptr, gP + (size_t)part * 262144, nullptr, 2048);
}

// ---------------------------------------------------------------------------
// Tail: 32 blocks = 2 kinds (hp/gp) x 4 N-tiles x 4 K-quarters.
// Each block recomputes its 128x128 h-slice (LSTM) from gate partials into
// LDS, then MFMAs hp/gp partials directly from LDS. Designated blocks
// (kind==0, nt==0) persist c and h (masked). t<0 = init from h0 (slot_prev).
__global__ __launch_bounds__(512) void k_tail(
    const ushort* __restrict__ xAll_c, ushort* __restrict__ xAll,
    const float* __restrict__ gP, const ushort* __restrict__ embG,
    const float* __restrict__ biascR, float* __restrict__ cbuf,
    const int* __restrict__ declen,
    const ushort* __restrict__ Wah, const ushort* __restrict__ Wb,
    float* __restrict__ hpP, float* __restrict__ gpP,
    int t, int slot_cur, int slot_prev)
{
  __shared__ ushort sH[128 * 136];
  __shared__ ushort Ws[128 * 72];
  const int tid = threadIdx.x;
  const int kind = blockIdx.x >> 4, sub = blockIdx.x & 15;
  const int nt = sub & 3, kq = sub >> 2;
  const int fbase = kq * 128;
  if (t >= 0) {
    for (int idx = tid; idx < 128 * 128; idx += 512) {
      int b = idx >> 7, fl = idx & 127;
      int f = fbase + fl;
      int row_t = t * 128 + b;
      float4 g0 = *(const float4*)&gP[(size_t)b * 2048 + f * 4];
      float4 g1 = *(const float4*)&gP[262144 + (size_t)b * 2048 + f * 4];
      ushort4 gev = *(const ushort4*)&embG[(size_t)row_t * 2048 + f * 4];
      float4 bc = *(const float4*)&biascR[f * 4];
      float i_ = g0.x + g1.x + bf2f(gev.x) + bc.x;
      float f_ = g0.y + g1.y + bf2f(gev.y) + bc.y;
      float g_ = g0.z + g1.z + bf2f(gev.z) + bc.z;
      float o_ = g0.w + g1.w + bf2f(gev.w) + bc.w;
      float cold = cbuf[b * 512 + f];
      float cn = sigmf(f_) * cold + sigmf(i_) * tanhf(g_);
      float hn = sigmf(o_) * tanhf(cn);
      bool act = t < declen[b];
      float hu = act ? hn
          : bf2f(xAll_c[((size_t)slot_prev * 128 + b) * 1536 + 1024 + f]);
      ushort hb = f2bf(hu);
      sH[b * 136 + fl] = hb;
      if (kind == 0 && nt == 0) {
        xAll[((size_t)slot_cur * 128 + b) * 1536 + 1024 + f] = hb;
        if (act) cbuf[b * 512 + f] = cn;
      }
    }
  } else {
    for (int idx = tid; idx < 128 * 128; idx += 512) {
      int b = idx >> 7, fl = idx & 127;
      sH[b * 136 + fl] =
          xAll_c[((size_t)slot_prev * 128 + b) * 1536 + 1024 + fbase + fl];
    }
  }
  // GEMM: partial (K=128) of h @ W^T, W rows nt*128..+128, cols fbase..+128
  const ushort* W = kind ? Wb : Wah;
  const int n0 = nt * 128;
  const int wv = tid >> 6, lane = tid & 63;
  const int rw = (wv & 1) * 64, cw = (wv >> 1) * 32;
  const int lrow = lane & 15, lk = (lane >> 4) * 8;
  f32x4 acc[4][2];
#pragma unroll
  for (int i = 0; i < 4; ++i)
#pragma unroll
    for (int j = 0; j < 2; ++j) acc[i][j] = (f32x4){0.f, 0.f, 0.f, 0.f};
  for (int k0 = 0; k0 < 128; k0 += 64) {
    __syncthreads();
#pragma unroll
    for (int it = 0; it < 2; ++it) {
      int row = it * 64 + (tid >> 3);
      int c8 = tid & 7;
      *(uint4*)&Ws[row * 72 + c8 * 8] =
          *(const uint4*)&W[(size_t)(n0 + row) * 512 + fbase + k0 + c8 * 8];
    }
    __syncthreads();
#pragma unroll
    for (int ks = 0; ks < 64; ks += 32) {
      bf16x8 af[4], bfr[2];
#pragma unroll
      for (int i = 0; i < 4; ++i)
        af[i] = *(const bf16x8*)&sH[(rw + i * 16 + lrow) * 136 + k0 + ks + lk];
#pragma unroll
      for (int j = 0; j < 2; ++j)
        bfr[j] = *(const bf16x8*)&Ws[(cw + j * 16 + lrow) * 72 + ks + lk];
#pragma unroll
      for (int i = 0; i < 4; ++i)
#pragma unroll
        for (int j = 0; j < 2; ++j)
          acc[i][j] = __builtin_amdgcn_mfma_f32_16x16x32_bf16(af[i], bfr[j],
                                                              acc[i][j], 0, 0, 0);
    }
  }
  float* outP = (kind ? gpP : hpP) + (size_t)kq * 65536;
  const int rsub = (lane >> 4) * 4;
#pragma unroll
  for (int i = 0; i < 4; ++i)
#pragma unroll
    for (int j = 0; j < 2; ++j) {
      int col = n0 + cw + j * 16 + lrow;
#pragma unroll
      for (int r = 0; r < 4; ++r)
        outP[(rw + i * 16 + rsub + r) * 512 + col] = acc[i][j][r];
    }
}

// ---------------------------------------------------------------------------
// Scores: 256 blocks = (b, l-half). Raw scores (softmax shift-invariance
// lets us drop b_att_v). hp = sum of 4 partials + fused bias.
__global__ __launch_bounds__(512) void k_score(
    const ushort* __restrict__ annp, const float* __restrict__ hpP,
    const float* __restrict__ b_hf, const float* __restrict__ wv_,
    float* __restrict__ scoresRaw)
{
  int b = blockIdx.x >> 1, lh = blockIdx.x & 1;
  int tid = threadIdx.x, lane = tid & 63, wvx = tid >> 6;
  int k0 = lane * 8;
  float hpv[8], wvv[8];
#pragma unroll
  for (int k = 0; k < 8; ++k) {
    int a = b * 512 + k0 + k;
    hpv[k] = hpP[a] + hpP[65536 + a] + hpP[131072 + a] + hpP[196608 + a]
           + b_hf[k0 + k];
    wvv[k] = wv_[k0 + k];
  }
  const int lbase = lh * 98;
  for (int l = lbase + wvx; l < lbase + 98; l += 8) {
    uint4 rv = *(const uint4*)&annp[((size_t)b * 196 + l) * 512 + k0];
    const ushort* rp = (const ushort*)&rv;
    float acc = 0.f;
#pragma unroll
    for (int k = 0; k < 8; ++k)
      acc = fmaf(fmaxf(bf2f(rp[k]) + hpv[k], 0.f), wvv[k], acc);
    for (int off = 32; off; off >>= 1) acc += __shfl_xor(acc, off, 64);
    if (lane == 0) scoresRaw[b * 256 + l] = acc;
  }
}

// ---------------------------------------------------------------------------
// Softmax + context + gate: 256 blocks = (b, f-half).
__global__ __launch_bounds__(512) void k_ctx(
    const ushort* __restrict__ ann_bf, const float* __restrict__ scoresRaw,
    const float* __restrict__ gpP, const float* __restrict__ b_beta,
    const int* __restrict__ declen, ushort* __restrict__ xAll,
    float* __restrict__ out_alpha, int t, int slot)
{
  int b = blockIdx.x >> 1, fh = blockIdx.x & 1;
  int tid = threadIdx.x, lane = tid & 63, wvx = tid >> 6;
  __shared__ float s_al[256];
  __shared__ float s_red[16];
  __shared__ float4 s_c4[512];
  float v = (tid < 196) ? scoresRaw[b * 256 + tid] : -3.402823466e38f;
  float m = v;
  for (int off = 32; off; off >>= 1) m = fmaxf(m, __shfl_xor(m, off, 64));
  if (lane == 0) s_red[wvx] = m;
  __syncthreads();
  m = s_red[0];
#pragma unroll
  for (int i = 1; i < 8; ++i) m = fmaxf(m, s_red[i]);
  float e = (tid < 196) ? expf(v - m) : 0.f;
  float s = e;
  for (int off = 32; off; off >>= 1) s += __shfl_xor(s, off, 64);
  if (lane == 0) s_red[8 + wvx] = s;
  __syncthreads();
  s = 0.f;
#pragma unroll
  for (int i = 0; i < 8; ++i) s += s_red[8 + i];
  float inv = 1.f / s;
  bool active = t < declen[b];
  if (tid < 196) {
    float al = e * inv;
    s_al[tid] = al;
    if (fh == 0) out_alpha[((size_t)b * 31 + t) * 196 + tid] = active ? al : 0.f;
  }
  __syncthreads();
  int fq = tid & 63, lg = tid >> 6;
  int f0 = fh * 256 + fq * 4;
  float4 cacc = make_float4(0.f, 0.f, 0.f, 0.f);
  for (int l = lg; l < 196; l += 8) {
    float a = s_al[l];
    ushort4 av = *(const ushort4*)&ann_bf[((size_t)b * 196 + l) * 512 + f0];
    cacc.x = fmaf(a, bf2f(av.x), cacc.x);
    cacc.y = fmaf(a, bf2f(av.y), cacc.y);
    cacc.z = fmaf(a, bf2f(av.z), cacc.z);
    cacc.w = fmaf(a, bf2f(av.w), cacc.w);
  }
  s_c4[tid] = cacc;
  __syncthreads();
  if (tid < 64) {
    float4 cs = make_float4(0.f, 0.f, 0.f, 0.f);
#pragma unroll
    for (int g = 0; g < 8; ++g) {
      float4 p = s_c4[g * 64 + tid];
      cs.x += p.x; cs.y += p.y; cs.z += p.z; cs.w += p.w;
    }
    int f1 = fh * 256 + tid * 4;
    int o = b * 512 + f1;
    float gpv[4];
#pragma unroll
    for (int k = 0; k < 4; ++k)
      gpv[k] = gpP[o + k] + gpP[65536 + o + k] + gpP[131072 + o + k]
             + gpP[196608 + o + k] + b_beta[f1 + k];
    ushort4 outv = make_ushort4(f2bf(sigmf(gpv[0]) * cs.x),
                                f2bf(sigmf(gpv[1]) * cs.y),
                                f2bf(sigmf(gpv[2]) * cs.z),
                                f2bf(sigmf(gpv[3]) * cs.w));
    *(ushort4*)&xAll[((size_t)slot * 128 + b) * 1536 + 512 + f1] = outv;
  }
}

// ---------------------------------------------------------------------------
// Prep: weight conversions + emb gather. Grid-stride.
__global__ __launch_bounds__(256) void k_prep(
    const float* __restrict__ W_ih, const float* __restrict__ W_hh,
    const float* __restrict__ b_ih, const float* __restrict__ b_hh,
    const float* __restrict__ W_y, const float* __restrict__ W_h,
    const float* __restrict__ W_z, const float* __restrict__ W_out,
    const float* __restrict__ W_att_f, const float* __restrict__ W_att_h,
    const float* __restrict__ W_beta, const float* __restrict__ b_att_f,
    const float* __restrict__ b_att_h, const float* __restrict__ ann,
    const int* __restrict__ captions, const float* __restrict__ E_emb,
    ushort* __restrict__ WgR, ushort* __restrict__ WgE,
    ushort* __restrict__ Wcat2_bf, ushort* __restrict__ Wo_bf,
    ushort* __restrict__ Waf_bf, ushort* __restrict__ Wah_bf,
    ushort* __restrict__ Wb_bf, ushort* __restrict__ ann_bf,
    ushort* __restrict__ xAll, float* __restrict__ biascR,
    float* __restrict__ b_hf)
{
  int idx = blockIdx.x * 256 + threadIdx.x;
  int stride = gridDim.x * 256;
  for (int i = idx; i < 12845056 / 8; i += stride)
    cvt8(ann + (size_t)i * 8, ann_bf + (size_t)i * 8);
  // WgR: 2048x1024 gate-interleaved [gctx|h]
  for (int i = idx; i < 2097152 / 8; i += stride) {
    int k8 = i * 8, rp = k8 >> 10, c = k8 & 1023;
    int f = rp >> 2, g = rp & 3;
    int r = g * 512 + f;
    const float* src = (c < 512) ? (W_ih + (size_t)r * 1024 + 512 + c)
                                 : (W_hh + (size_t)r * 512 + c - 512);
    cvt8(src, WgR + k8);
  }
  // WgE: 2048x512 gate-interleaved emb weights
  for (int i = idx; i < 1048576 / 8; i += stride) {
    int k8 = i * 8, rp = k8 >> 9, c = k8 & 511;
    int f = rp >> 2, g = rp & 3;
    int r = g * 512 + f;
    cvt8(W_ih + (size_t)r * 1024 + c, WgE + k8);
  }
  // Wcat2: 512x1536 [W_y|W_z|W_h] matching xAll [emb|gctx|h]
  for (int i = idx; i < 786432 / 8; i += stride) {
    int k8 = i * 8, r = k8 / 1536, c = k8 - r * 1536;
    const float* src = (c < 512) ? (W_y + (size_t)r * 512 + c)
                     : (c < 1024 ? (W_z + (size_t)r * 512 + c - 512)
                                 : (W_h + (size_t)r * 512 + c - 1024));
    cvt8(src, Wcat2_bf + k8);
  }
  for (int i = idx; i < 5177344 / 8; i += stride) {   // Wo: 10112x512, pad 0
    int r = i >> 6, c8 = i & 63;
    if (r < 10000) cvt8(W_out + (size_t)r * 512 + c8 * 8, Wo_bf + (size_t)i * 8);
    else { *(uint4*)(Wo_bf + (size_t)i * 8) = make_uint4(0, 0, 0, 0); }
  }
  for (int i = idx; i < 262144 / 8; i += stride) {
    cvt8(W_att_f + i * 8, Waf_bf + i * 8);
    cvt8(W_att_h + i * 8, Wah_bf + i * 8);
    cvt8(W_beta + i * 8, Wb_bf + i * 8);
  }
  // embAll gather into xAll[:, 0:512] slots 0..30
  for (int i = idx; i < 3968 * 64; i += stride) {
    int row = i >> 6, c8 = (i & 63) * 8;
    int tt = row >> 7, bb = row & 127;
    int tok = captions[bb * 32 + tt];
    cvt8(E_emb + (size_t)tok * 512 + c8, xAll + (size_t)row * 1536 + c8);
  }
  for (int i = idx; i < 2048; i += stride) {
    int f = i >> 2, g = i & 3;
    biascR[i] = b_ih[g * 512 + f] + b_hh[g * 512 + f];
  }
  for (int i = idx; i < 512; i += stride) b_hf[i] = b_att_h[i] + b_att_f[i];
}

// mean over L, dec_len
__global__ __launch_bounds__(256) void k_mean(
    const float* __restrict__ ann, const int* __restrict__ lengths,
    float* __restrict__ meanb, int* __restrict__ declen, float* __restrict__ out_dec)
{
  int b = blockIdx.x, tid = threadIdx.x;
  const float* ab = ann + (size_t)b * 196 * 512;
  for (int f = tid; f < 512; f += 256) {
    float s = 0.f;
    for (int l = 0; l < 196; ++l) s += ab[l * 512 + f];
    meanb[b * 512 + f] = s * (1.f / 196.f);
  }
  if (tid == 0) {
    int d = lengths[b] - 1;
    if (d < 1) d = 1;
    declen[b] = d;
    out_dec[b] = (float)d;
  }
}

// fp32 32x64-tile GEMM for h0/c0 init (tiny).
DEV float actf(float v, int act) { return act == 2 ? tanhf(v) : v; }
__global__ __launch_bounds__(256) void gemm32_k(
    const float* __restrict__ A, int lda, const float* __restrict__ W, int ldw,
    const float* __restrict__ bias, float* __restrict__ C, int ldc, int K, int act)
{
  __shared__ float As[32 * 36];
  __shared__ float Ws[32 * 68];
  const int tid = threadIdx.x;
  const int m0 = blockIdx.y * 32, n0 = blockIdx.x * 64;
  const int tx = tid & 15, ty = tid >> 4;
  const int r0 = ty * 2, c0 = tx * 4;
  const int lr = tid >> 3, lk = (tid & 7) * 4;
  const float* Ap = A + (size_t)(m0 + lr) * lda + lk;
  const float* Wp0 = W + (size_t)(n0 + lr) * ldw + lk;
  const float* Wp1 = W + (size_t)(n0 + lr + 32) * ldw + lk;
  float acc[2][4] = {{0.f, 0.f, 0.f, 0.f}, {0.f, 0.f, 0.f, 0.f}};
  for (int k0 = 0; k0 < K; k0 += 32) {
    float4 av = *(const float4*)(Ap + k0);
    float4 w0 = *(const float4*)(Wp0 + k0);
    float4 w1 = *(const float4*)(Wp1 + k0);
    __syncthreads();
    As[(lk + 0) * 36 + lr] = av.x; As[(lk + 1) * 36 + lr] = av.y;
    As[(lk + 2) * 36 + lr] = av.z; As[(lk + 3) * 36 + lr] = av.w;
    Ws[(lk + 0) * 68 + lr] = w0.x; Ws[(lk + 1) * 68 + lr] = w0.y;
    Ws[(lk + 2) * 68 + lr] = w0.z; Ws[(lk + 3) * 68 + lr] = w0.w;
    Ws[(lk + 0) * 68 + lr + 32] = w1.x; Ws[(lk + 1) * 68 + lr + 32] = w1.y;
    Ws[(lk + 2) * 68 + lr + 32] = w1.z; Ws[(lk + 3) * 68 + lr + 32] = w1.w;
    __syncthreads();
#pragma unroll
    for (int kk = 0; kk < 32; ++kk) {
      float2 a = *(const float2*)&As[kk * 36 + r0];
      float4 w = *(const float4*)&Ws[kk * 68 + c0];
      const float aa[2] = {a.x, a.y};
      const float* wwp = (const float*)&w;
#pragma unroll
      for (int i = 0; i < 2; ++i)
#pragma unroll
        for (int j = 0; j < 4; ++j)
          acc[i][j] = fmaf(aa[i], wwp[j], acc[i][j]);
    }
  }
#pragma unroll
  for (int i = 0; i < 2; ++i)
#pragma unroll
    for (int j = 0; j < 4; ++j)
      C[(size_t)(m0 + r0 + i) * ldc + n0 + c0 + j] =
          actf(acc[i][j] + bias[n0 + c0 + j], act);
}

// h0 -> xAll slot 31 (bf16)
__global__ __launch_bounds__(256) void k_cvt_h0(
    const float* __restrict__ h0f, ushort* __restrict__ xAll)
{
  int idx = blockIdx.x * 256 + threadIdx.x;   // 65536
  int b = idx >> 9, j = idx & 511;
  xAll[((size_t)31 * 128 + b) * 1536 + 1024 + j] = f2bf(h0f[idx]);
}

// ---------------------------------------------------------------------------
extern "C" void kernel_launch(void* const* d_in, const int* in_sizes, int n_in,
                              void* d_out, int out_size, void* d_ws, size_t ws_size,
                              hipStream_t stream)
{
  const float* ann      = (const float*)d_in[0];
  const int*   captions = (const int*)d_in[1];
  const int*   lengths  = (const int*)d_in[2];
  const float* E_emb    = (const float*)d_in[3];
  const float* W_init_h = (const float*)d_in[4];
  const float* b_init_h = (const float*)d_in[5];
  const float* W_init_c = (const float*)d_in[6];
  const float* b_init_c = (const float*)d_in[7];
  const float* W_att_f  = (const float*)d_in[8];
  const float* b_att_f  = (const float*)d_in[9];
  const float* W_att_h  = (const float*)d_in[10];
  const float* b_att_h  = (const float*)d_in[11];
  const float* w_att_v  = (const float*)d_in[12];
  const float* b_att_v  = (const float*)d_in[13];  // unused (softmax invariant)
  const float* W_beta   = (const float*)d_in[14];
  const float* b_beta   = (const float*)d_in[15];
  const float* W_ih     = (const float*)d_in[16];
  const float* W_hh     = (const float*)d_in[17];
  const float* b_ih     = (const float*)d_in[18];
  const float* b_hh     = (const float*)d_in[19];
  const float* W_y      = (const float*)d_in[20];
  const float* W_h      = (const float*)d_in[21];
  const float* W_z      = (const float*)d_in[22];
  const float* W_out    = (const float*)d_in[23];
  const float* b_out    = (const float*)d_in[24];

  float* out        = (float*)d_out;
  float* out_logits = out;
  float* out_alpha  = out + 39680000ll;
  float* out_dec    = out + 40457728ll;

  char* p = (char*)d_ws;
  auto alloc_us = [&](size_t n) { ushort* r = (ushort*)p; p += ((n * 2 + 255) & ~(size_t)255); return r; };
  auto alloc_f  = [&](size_t n) { float*  r = (float*)p;  p += ((n * 4 + 255) & ~(size_t)255); return r; };
  ushort* Wo_bf    = alloc_us(10112 * 512);
  ushort* WgR_bf   = alloc_us(2048 * 1024);
  ushort* WgE_bf   = alloc_us(2048 * 512);
  ushort* Wcat2_bf = alloc_us(512 * 1536);
  ushort* Waf_bf   = alloc_us(512 * 512);
  ushort* Wah_bf   = alloc_us(512 * 512);
  ushort* Wb_bf    = alloc_us(512 * 512);
  ushort* ann_bf   = alloc_us(12845056);
  ushort* annp_bf  = alloc_us(12845056);
  ushort* preA_bf  = alloc_us(3968 * 512);
  ushort* xAll     = alloc_us(32 * 128 * 1536);
  ushort* embG     = alloc_us(3968 * 2048);
  float* biascR = alloc_f(2048);
  float* b_hf   = alloc_f(512);
  float* hpP    = alloc_f(4 * 65536);
  float* gpP    = alloc_f(4 * 65536);
  float* gP     = alloc_f(2 * 262144);
  float* scoresRaw = alloc_f(128 * 256);
  float* cbuf   = alloc_f(65536);
  float* meanb  = alloc_f(65536);
  float* h0f    = alloc_f(65536);
  int*   declen = (int*)alloc_f(128);

  // ---- phase 1 ----
  hipLaunchKernelGGL(k_prep, dim3(1024), dim3(256), 0, stream,
                     W_ih, W_hh, b_ih, b_hh, W_y, W_h, W_z, W_out,
                     W_att_f, W_att_h, W_beta, b_att_f, b_att_h, ann,
                     captions, E_emb,
                     WgR_bf, WgE_bf, Wcat2_bf, Wo_bf, Waf_bf, Wah_bf, Wb_bf,
                     ann_bf, xAll, biascR, b_hf);
  hipLaunchKernelGGL(k_mean, dim3(128), dim3(256), 0, stream,
                     ann, lengths, meanb, declen, out_dec);
  hipLaunchKernelGGL(gemm32_k, dim3(8, 4), dim3(256), 0, stream,
                     meanb, 512, W_init_h, 512, b_init_h, h0f, 512, 512, 2);
  hipLaunchKernelGGL(gemm32_k, dim3(8, 4), dim3(256), 0, stream,
                     meanb, 512, W_init_c, 512, b_init_c, cbuf, 512, 512, 2);
  hipLaunchKernelGGL(k_cvt_h0, dim3(256), dim3(256), 0, stream, h0f, xAll);
  // annp = ann_bf @ Waf^T (bf16)
  hipLaunchKernelGGL(k_mfma, dim3(4, 196), dim3(256), 0, stream,
                     ann_bf, 512, Waf_bf, 512, 512, 1, (const float*)nullptr,
                     (float*)nullptr, annp_bf, 512);
  // embG = embAll @ WgE^T (bf16, 3968x2048)
  hipLaunchKernelGGL(k_mfma, dim3(16, 31), dim3(256), 0, stream,
                     xAll, 1536, WgE_bf, 512, 512, 1, (const float*)nullptr,
                     (float*)nullptr, embG, 2048);
  // init hp/gp from h0 (slot 31)
  hipLaunchKernelGGL(k_tail, dim3(32), dim3(512), 0, stream,
                     xAll, xAll, gP, embG, biascR, cbuf, declen,
                     Wah_bf, Wb_bf, hpP, gpP, -1, 31, 31);

  // ---- phase 2: 31 steps ----
  for (int t = 0; t < 31; ++t) {
    int prev = (t == 0) ? 31 : t - 1;
    hipLaunchKernelGGL(k_score, dim3(256), dim3(512), 0, stream,
                       annp_bf, hpP, b_hf, w_att_v, scoresRaw);
    hipLaunchKernelGGL(k_ctx, dim3(256), dim3(512), 0, stream,
                       ann_bf, scoresRaw, gpP, b_beta, declen, xAll,
                       out_alpha, t, t);
    hipLaunchKernelGGL(k_gates, dim3(32), dim3(256), 0, stream,
                       xAll, WgR_bf, gP, t, prev);
    hipLaunchKernelGGL(k_tail, dim3(32), dim3(512), 0, stream,
                       xAll, xAll, gP, embG, biascR, cbuf, declen,
                       Wah_bf, Wb_bf, hpP, gpP, t, t, prev);
  }

  // ---- phase 3: pre = tanh(xAll @ Wcat2^T); logits ----
  hipLaunchKernelGGL(k_mfma, dim3(4, 31), dim3(256), 0, stream,
                     xAll, 1536, Wcat2_bf, 1536, 1536, 2, (const float*)nullptr,
                     (float*)nullptr, preA_bf, 512);
  hipLaunchKernelGGL(k_logits, dim3(2480), dim3(256), 0, stream,
                     preA_bf, Wo_bf, b_out, out_logits, declen);
}

// Round 5
// 1767.168 us; speedup vs baseline: 1.4880x; 1.4880x over previous
//
#include <hip/hip_runtime.h>
#include <cstdint>

// AttentionDecoder: B=128, L=196, T_dec=31, E=H=F=A=512, V=10000
// Out: logits (128*31*10000) | alphas (128*31*196) | dec_len (128), fp32.
//
// Structure: emb gate-contributions precomputed for all steps (teacher
// forcing); pre GEMM batched at the end; per-step chain:
//   k_attn (hp/gp partial-sum + score + softmax + context + gate)
//   -> k_gates (split gctx/h, K=512 each)
//   -> k_lstm  (single-writer pointwise, h -> xAll slot t)
//   -> k_tail  (hp/gp split-K GEMMs, 4 partials each)

#define DEV __device__ __forceinline__

typedef __bf16 bf16x8 __attribute__((ext_vector_type(8)));
typedef float  f32x4  __attribute__((ext_vector_type(4)));

DEV float sigmf(float v) { return 1.f / (1.f + expf(-v)); }

DEV ushort f2bf(float f) {
  union { float f; uint32_t u; } c; c.f = f;
  uint32_t u = c.u;
  return (ushort)((u + 0x7FFFu + ((u >> 16) & 1u)) >> 16);
}
DEV float bf2f(ushort h) {
  union { uint32_t u; float f; } c; c.u = ((uint32_t)h) << 16;
  return c.f;
}
DEV void cvt8(const float* __restrict__ s, ushort* __restrict__ d) {
  float4 a = *(const float4*)s;
  float4 b = *(const float4*)(s + 4);
  *(ushort4*)d = make_ushort4(f2bf(a.x), f2bf(a.y), f2bf(a.z), f2bf(a.w));
  *(ushort4*)(d + 4) = make_ushort4(f2bf(b.x), f2bf(b.y), f2bf(b.z), f2bf(b.w));
}

// ---------------------------------------------------------------------------
// 128x128-tile bf16 MFMA GEMM tile body (256 thr = 4 waves, 64x64/wave).
// mode 0: fp32 out (+bias if non-null); 1: bf16 out; 2: bf16 out tanh.
DEV void mfma_body(ushort* As, ushort* Ws, int mt, int nt,
                   const ushort* __restrict__ A, int lda,
                   const ushort* __restrict__ W, int ldw,
                   int K, int mode, const float* __restrict__ bias,
                   float* __restrict__ Cf, ushort* __restrict__ Cb, int ldc)
{
  const int tid = threadIdx.x;
  const int m0 = mt * 128, n0 = nt * 128;
  const int wv = tid >> 6, lane = tid & 63;
  const int rw = (wv & 1) * 64, cw = (wv >> 1) * 64;
  const int lrow = lane & 15, lk = (lane >> 4) * 8;
  f32x4 acc[4][4];
#pragma unroll
  for (int i = 0; i < 4; ++i)
#pragma unroll
    for (int j = 0; j < 4; ++j) acc[i][j] = (f32x4){0.f, 0.f, 0.f, 0.f};

  const int srow = tid >> 3;
  const int sc8  = tid & 7;
  for (int k0 = 0; k0 < K; k0 += 64) {
    __syncthreads();
#pragma unroll
    for (int it = 0; it < 4; ++it) {
      int row = it * 32 + srow;
      *(uint4*)&As[row * 72 + sc8 * 8] =
          *(const uint4*)&A[(size_t)(m0 + row) * lda + k0 + sc8 * 8];
      *(uint4*)&Ws[row * 72 + sc8 * 8] =
          *(const uint4*)&W[(size_t)(n0 + row) * ldw + k0 + sc8 * 8];
    }
    __syncthreads();
#pragma unroll
    for (int ks = 0; ks < 64; ks += 32) {
      bf16x8 af[4], bfr[4];
#pragma unroll
      for (int i = 0; i < 4; ++i)
        af[i] = *(const bf16x8*)&As[(rw + i * 16 + lrow) * 72 + ks + lk];
#pragma unroll
      for (int j = 0; j < 4; ++j)
        bfr[j] = *(const bf16x8*)&Ws[(cw + j * 16 + lrow) * 72 + ks + lk];
#pragma unroll
      for (int i = 0; i < 4; ++i)
#pragma unroll
        for (int j = 0; j < 4; ++j)
          acc[i][j] = __builtin_amdgcn_mfma_f32_16x16x32_bf16(af[i], bfr[j],
                                                              acc[i][j], 0, 0, 0);
    }
  }
  const int rsub = (lane >> 4) * 4;
#pragma unroll
  for (int i = 0; i < 4; ++i) {
#pragma unroll
    for (int j = 0; j < 4; ++j) {
      int col = n0 + cw + j * 16 + lrow;
#pragma unroll
      for (int r = 0; r < 4; ++r) {
        int row = m0 + rw + i * 16 + rsub + r;
        float v = acc[i][j][r];
        if (mode == 0)      Cf[(size_t)row * ldc + col] = bias ? v + bias[col] : v;
        else if (mode == 1) Cb[(size_t)row * ldc + col] = f2bf(v);
        else                Cb[(size_t)row * ldc + col] = f2bf(tanhf(v));
      }
    }
  }
}

__global__ __launch_bounds__(256) void k_mfma(
    const ushort* __restrict__ A, int lda, const ushort* __restrict__ W, int ldw,
    int K, int mode, const float* __restrict__ bias,
    float* __restrict__ Cf, ushort* __restrict__ Cb, int ldc)
{
  __shared__ ushort As[128 * 72];
  __shared__ ushort Ws[128 * 72];
  mfma_body(As, Ws, blockIdx.y, blockIdx.x, A, lda, W, ldw, K, mode, bias,
            Cf, Cb, ldc);
}

// ---------------------------------------------------------------------------
// Logits GEMM with XCD-localizing swizzle + LDS-staged coalesced epilogue.
__global__ __launch_bounds__(256) void k_logits(
    const ushort* __restrict__ preA, const ushort* __restrict__ Wo,
    const float* __restrict__ b_out, float* __restrict__ out_logits,
    const int* __restrict__ declen)
{
  __shared__ ushort SMEM[2 * 128 * 72];
  ushort* As = SMEM;
  ushort* Ws = SMEM + 128 * 72;
  int id = blockIdx.x;
  int x = id & 7, g = id >> 3;
  int G = g / 31, row_t = g - G * 31;
  int colt = G * 8 + x;
  if (colt >= 79) return;
  const int tid = threadIdx.x;
  const int m0 = row_t * 128, n0 = colt * 128;
  const int wv = tid >> 6, lane = tid & 63;
  const int rw = (wv & 1) * 64, cw = (wv >> 1) * 64;
  const int lrow = lane & 15, lk = (lane >> 4) * 8;
  f32x4 acc[4][4];
#pragma unroll
  for (int i = 0; i < 4; ++i)
#pragma unroll
    for (int j = 0; j < 4; ++j) acc[i][j] = (f32x4){0.f, 0.f, 0.f, 0.f};
  const int srow = tid >> 3, sc8 = tid & 7;
  for (int k0 = 0; k0 < 512; k0 += 64) {
    __syncthreads();
#pragma unroll
    for (int it = 0; it < 4; ++it) {
      int row = it * 32 + srow;
      *(uint4*)&As[row * 72 + sc8 * 8] =
          *(const uint4*)&preA[(size_t)(m0 + row) * 512 + k0 + sc8 * 8];
      *(uint4*)&Ws[row * 72 + sc8 * 8] =
          *(const uint4*)&Wo[(size_t)(n0 + row) * 512 + k0 + sc8 * 8];
    }
    __syncthreads();
#pragma unroll
    for (int ks = 0; ks < 64; ks += 32) {
      bf16x8 af[4], bfr[4];
#pragma unroll
      for (int i = 0; i < 4; ++i)
        af[i] = *(const bf16x8*)&As[(rw + i * 16 + lrow) * 72 + ks + lk];
#pragma unroll
      for (int j = 0; j < 4; ++j)
        bfr[j] = *(const bf16x8*)&Ws[(cw + j * 16 + lrow) * 72 + ks + lk];
#pragma unroll
      for (int i = 0; i < 4; ++i)
#pragma unroll
        for (int j = 0; j < 4; ++j)
          acc[i][j] = __builtin_amdgcn_mfma_f32_16x16x32_bf16(af[i], bfr[j],
                                                              acc[i][j], 0, 0, 0);
    }
  }
  // epilogue: stage 64x128 fp32 half-tiles in LDS, write coalesced float4 rows
  float* sC = (float*)SMEM;   // 64*132 floats = 33.8 KB
  const int rsub = (lane >> 4) * 4;
  for (int rh = 0; rh < 2; ++rh) {
    __syncthreads();
    if ((wv & 1) == rh) {
#pragma unroll
      for (int i = 0; i < 4; ++i)
#pragma unroll
        for (int j = 0; j < 4; ++j)
#pragma unroll
          for (int r = 0; r < 4; ++r)
            sC[(i * 16 + rsub + r) * 132 + cw + j * 16 + lrow] = acc[i][j][r];
    }
    __syncthreads();
    for (int q = tid; q < 2048; q += 256) {
      int r = q >> 5, qc = q & 31;
      int grow = m0 + rh * 64 + r;          // = t*128 + b
      int tt = grow >> 7, bb = grow & 127;
      bool act = tt < declen[bb];
      int c0 = n0 + qc * 4;
      float4 v = *(float4*)&sC[r * 132 + qc * 4];
      if (act) {
        v.x += b_out[c0]; v.y += b_out[c0 + 1];
        v.z += b_out[c0 + 2]; v.w += b_out[c0 + 3];
      } else v = make_float4(0.f, 0.f, 0.f, 0.f);
      float* dst = out_logits + ((size_t)bb * 31 + tt) * 10000 + c0;
      if (c0 + 3 < 10000) *(float4*)dst = v;
      else {
        const float vv[4] = {v.x, v.y, v.z, v.w};
        for (int k = 0; k < 4; ++k) if (c0 + k < 10000) dst[k] = vv[k];
      }
    }
  }
}

// ---------------------------------------------------------------------------
// Gates GEMM: 32 blocks = 16 N-tiles x 2 parts (part0 gctx@slot_cur,
// part1 h@slot_prev). K=512 each. fp32 partials gP[part].
__global__ __launch_bounds__(256) void k_gates(
    const ushort* __restrict__ xAll, const ushort* __restrict__ WgR,
    float* __restrict__ gP, int slot_cur, int slot_prev)
{
  __shared__ ushort As[128 * 72];
  __shared__ ushort Ws[128 * 72];
  int part = blockIdx.x >> 4, nt = blockIdx.x & 15;
  const ushort* A = xAll + (size_t)(part == 0 ? slot_cur : slot_prev) * 196608
                         + (part == 0 ? 512 : 1024);
  mfma_body(As, Ws, 0, nt, A, 1536, WgR + part * 512, 1024, 512, 0,
            nullptr, gP + (size_t)part * 262144, nullptr, 2048);
}

// ---------------------------------------------------------------------------
// LSTM pointwise (single writer, no race): sums gctx/h gate partials +
// embG[t] + bias (gate-interleaved float4), masked update. h -> xAll slot t.
__global__ __launch_bounds__(256) void k_lstm(
    const float* __restrict__ gP, const ushort* __restrict__ embG,
    const float* __restrict__ biascR, float* __restrict__ cbuf,
    const int* __restrict__ declen, ushort* __restrict__ xAll,
    int t, int slot_prev)
{
  int idx = blockIdx.x * 256 + threadIdx.x;   // 65536
  int b = idx >> 9, f = idx & 511;
  ushort* dst = &xAll[((size_t)t * 128 + b) * 1536 + 1024 + f];
  if (t >= declen[b]) {
    *dst = xAll[((size_t)slot_prev * 128 + b) * 1536 + 1024 + f];
    return;
  }
  float4 g0 = *(const float4*)&gP[(size_t)b * 2048 + f * 4];
  float4 g1 = *(const float4*)&gP[262144 + (size_t)b * 2048 + f * 4];
  ushort4 ge = *(const ushort4*)&embG[((size_t)t * 128 + b) * 2048 + f * 4];
  float4 bc = *(const float4*)&biascR[f * 4];
  float i_ = g0.x + g1.x + bf2f(ge.x) + bc.x;
  float f_ = g0.y + g1.y + bf2f(ge.y) + bc.y;
  float g_ = g0.z + g1.z + bf2f(ge.z) + bc.z;
  float o_ = g0.w + g1.w + bf2f(ge.w) + bc.w;
  float cn = sigmf(f_) * cbuf[idx] + sigmf(i_) * tanhf(g_);
  float hn = sigmf(o_) * tanhf(cn);
  cbuf[idx] = cn;
  *dst = f2bf(hn);
}

// ---------------------------------------------------------------------------
// Tail: hp/gp split-K GEMMs. 32 blocks = 2 kinds x 4 N-tiles x 4 K-quarters
// (K=128 each). Partials summed inside k_attn.
__global__ __launch_bounds__(256) void k_tail(
    const ushort* __restrict__ xAll,
    const ushort* __restrict__ Wah, const ushort* __restrict__ Wb,
    float* __restrict__ hpP, float* __restrict__ gpP, int slot)
{
  __shared__ ushort As[128 * 72];
  __shared__ ushort Ws[128 * 72];
  int kind = blockIdx.x >> 4, sub = blockIdx.x & 15;
  int nt = sub & 3, ks = sub >> 2;
  const ushort* A = xAll + (size_t)slot * 196608 + 1024 + ks * 128;
  const ushort* W = (kind ? Wb : Wah) + ks * 128;
  float* outP = (kind ? gpP : hpP) + (size_t)ks * 65536;
  mfma_body(As, Ws, 0, nt, A, 1536, W, 512, 128, 0, nullptr, outP, nullptr, 512);
}

// ---------------------------------------------------------------------------
// Fused attention step (128 blocks x 1024 thr): sums hp partials (+bias),
// scores from annp, softmax -> alpha (masked), context over ann, gate from
// gp partials, gctx (bf16) -> xAll slot t. emb already staged by k_prep.
__global__ __launch_bounds__(1024) void k_attn(
    const ushort* __restrict__ annp_bf, const ushort* __restrict__ ann_bf,
    const float* __restrict__ hpP, const float* __restrict__ gpP,
    const float* __restrict__ b_hf, const float* __restrict__ b_beta,
    const float* __restrict__ wv_, const int* __restrict__ declen,
    ushort* __restrict__ xAll, float* __restrict__ out_alpha, int t)
{
  int b = blockIdx.x, tid = threadIdx.x;
  int lane = tid & 63, wvx = tid >> 6;   // 16 waves
  __shared__ float s_hp[512];
  __shared__ float s_wv[512];
  __shared__ float s_sc[196];
  __shared__ float s_red[32];
  __shared__ float s_ctx[1024];
  if (tid < 512) {
    int o = b * 512 + tid;
    s_hp[tid] = hpP[o] + hpP[65536 + o] + hpP[131072 + o] + hpP[196608 + o]
              + b_hf[tid];
  } else {
    s_wv[tid - 512] = wv_[tid - 512];
  }
  __syncthreads();
  const ushort* ap = annp_bf + (size_t)b * 196 * 512;
  for (int l = wvx; l < 196; l += 16) {
    const ushort* row = ap + l * 512;
    float acc = 0.f;
#pragma unroll
    for (int a0 = 0; a0 < 512; a0 += 256) {
      ushort4 rv = *(const ushort4*)(row + a0 + lane * 4);
      float4 hv = *(const float4*)&s_hp[a0 + lane * 4];
      float4 wt = *(const float4*)&s_wv[a0 + lane * 4];
      acc = fmaf(fmaxf(bf2f(rv.x) + hv.x, 0.f), wt.x, acc);
      acc = fmaf(fmaxf(bf2f(rv.y) + hv.y, 0.f), wt.y, acc);
      acc = fmaf(fmaxf(bf2f(rv.z) + hv.z, 0.f), wt.z, acc);
      acc = fmaf(fmaxf(bf2f(rv.w) + hv.w, 0.f), wt.w, acc);
    }
    for (int off = 32; off; off >>= 1) acc += __shfl_xor(acc, off, 64);
    if (lane == 0) s_sc[l] = acc;
  }
  __syncthreads();
  float v = (tid < 196) ? s_sc[tid] : -3.402823466e38f;
  float m = v;
  for (int off = 32; off; off >>= 1) m = fmaxf(m, __shfl_xor(m, off, 64));
  if (lane == 0) s_red[wvx] = m;
  __syncthreads();
  m = s_red[0];
#pragma unroll
  for (int i = 1; i < 16; ++i) m = fmaxf(m, s_red[i]);
  float e = (tid < 196) ? expf(v - m) : 0.f;
  float s = e;
  for (int off = 32; off; off >>= 1) s += __shfl_xor(s, off, 64);
  if (lane == 0) s_red[16 + wvx] = s;
  __syncthreads();
  s = 0.f;
#pragma unroll
  for (int i = 0; i < 16; ++i) s += s_red[16 + i];
  float inv = 1.f / s;
  bool active = t < declen[b];
  if (tid < 196) {
    float al = e * inv;
    s_sc[tid] = al;
    out_alpha[((size_t)b * 31 + t) * 196 + tid] = active ? al : 0.f;
  }
  __syncthreads();
  // context: two halves over l
  int half = tid >> 9, f = tid & 511;
  const ushort* ab = ann_bf + (size_t)b * 196 * 512 + (size_t)half * 98 * 512 + f;
  const float* scp = &s_sc[half * 98];
  float ctx = 0.f;
#pragma unroll 7
  for (int l = 0; l < 98; ++l) ctx = fmaf(scp[l], bf2f(ab[(size_t)l * 512]), ctx);
  s_ctx[tid] = ctx;
  __syncthreads();
  if (tid < 512) {
    float cv = s_ctx[tid] + s_ctx[tid + 512];
    int o = b * 512 + tid;
    float gp = gpP[o] + gpP[65536 + o] + gpP[131072 + o] + gpP[196608 + o]
             + b_beta[tid];
    xAll[((size_t)t * 128 + b) * 1536 + 512 + tid] = f2bf(sigmf(gp) * cv);
  }
}

// ---------------------------------------------------------------------------
// Prep: weight conversions + emb gather into xAll slots. Grid-stride.
__global__ __launch_bounds__(256) void k_prep(
    const float* __restrict__ W_ih, const float* __restrict__ W_hh,
    const float* __restrict__ b_ih, const float* __restrict__ b_hh,
    const float* __restrict__ W_y, const float* __restrict__ W_h,
    const float* __restrict__ W_z, const float* __restrict__ W_out,
    const float* __restrict__ W_att_f, const float* __restrict__ W_att_h,
    const float* __restrict__ W_beta, const float* __restrict__ b_att_f,
    const float* __restrict__ b_att_h, const float* __restrict__ ann,
    const int* __restrict__ captions, const float* __restrict__ E_emb,
    ushort* __restrict__ WgR, ushort* __restrict__ WgE,
    ushort* __restrict__ Wcat2_bf, ushort* __restrict__ Wo_bf,
    ushort* __restrict__ Waf_bf, ushort* __restrict__ Wah_bf,
    ushort* __restrict__ Wb_bf, ushort* __restrict__ ann_bf,
    ushort* __restrict__ xAll, float* __restrict__ biascR,
    float* __restrict__ b_hf)
{
  int idx = blockIdx.x * 256 + threadIdx.x;
  int stride = gridDim.x * 256;
  for (int i = idx; i < 12845056 / 8; i += stride)
    cvt8(ann + (size_t)i * 8, ann_bf + (size_t)i * 8);
  // WgR: 2048x1024 gate-interleaved [gctx|h]
  for (int i = idx; i < 2097152 / 8; i += stride) {
    int k8 = i * 8, rp = k8 >> 10, c = k8 & 1023;
    int f = rp >> 2, g = rp & 3;
    int r = g * 512 + f;
    const float* src = (c < 512) ? (W_ih + (size_t)r * 1024 + 512 + c)
                                 : (W_hh + (size_t)r * 512 + c - 512);
    cvt8(src, WgR + k8);
  }
  // WgE: 2048x512 gate-interleaved emb weights
  for (int i = idx; i < 1048576 / 8; i += stride) {
    int k8 = i * 8, rp = k8 >> 9, c = k8 & 511;
    int f = rp >> 2, g = rp & 3;
    int r = g * 512 + f;
    cvt8(W_ih + (size_t)r * 1024 + c, WgE + k8);
  }
  // Wcat2: 512x1536 [W_y|W_z|W_h] matching xAll [emb|gctx|h]
  for (int i = idx; i < 786432 / 8; i += stride) {
    int k8 = i * 8, r = k8 / 1536, c = k8 - r * 1536;
    const float* src = (c < 512) ? (W_y + (size_t)r * 512 + c)
                     : (c < 1024 ? (W_z + (size_t)r * 512 + c - 512)
                                 : (W_h + (size_t)r * 512 + c - 1024));
    cvt8(src, Wcat2_bf + k8);
  }
  for (int i = idx; i < 5177344 / 8; i += stride) {   // Wo: 10112x512, pad 0
    int r = i >> 6, c8 = i & 63;
    if (r < 10000) cvt8(W_out + (size_t)r * 512 + c8 * 8, Wo_bf + (size_t)i * 8);
    else { *(uint4*)(Wo_bf + (size_t)i * 8) = make_uint4(0, 0, 0, 0); }
  }
  for (int i = idx; i < 262144 / 8; i += stride) {
    cvt8(W_att_f + i * 8, Waf_bf + i * 8);
    cvt8(W_att_h + i * 8, Wah_bf + i * 8);
    cvt8(W_beta + i * 8, Wb_bf + i * 8);
  }
  // embAll gather into xAll[:, 0:512] slots 0..30
  for (int i = idx; i < 3968 * 64; i += stride) {
    int row = i >> 6, c8 = (i & 63) * 8;
    int tt = row >> 7, bb = row & 127;
    int tok = captions[bb * 32 + tt];
    cvt8(E_emb + (size_t)tok * 512 + c8, xAll + (size_t)row * 1536 + c8);
  }
  for (int i = idx; i < 2048; i += stride) {
    int f = i >> 2, g = i & 3;
    biascR[i] = b_ih[g * 512 + f] + b_hh[g * 512 + f];
  }
  for (int i = idx; i < 512; i += stride) b_hf[i] = b_att_h[i] + b_att_f[i];
}

// mean over L, dec_len
__global__ __launch_bounds__(256) void k_mean(
    const float* __restrict__ ann, const int* __restrict__ lengths,
    float* __restrict__ meanb, int* __restrict__ declen, float* __restrict__ out_dec)
{
  int b = blockIdx.x, tid = threadIdx.x;
  const float* ab = ann + (size_t)b * 196 * 512;
  for (int f = tid; f < 512; f += 256) {
    float s = 0.f;
    for (int l = 0; l < 196; ++l) s += ab[l * 512 + f];
    meanb[b * 512 + f] = s * (1.f / 196.f);
  }
  if (tid == 0) {
    int d = lengths[b] - 1;
    if (d < 1) d = 1;
    declen[b] = d;
    out_dec[b] = (float)d;
  }
}

// fp32 32x64-tile GEMM for h0/c0 init (tiny).
DEV float actf(float v, int act) { return act == 2 ? tanhf(v) : v; }
__global__ __launch_bounds__(256) void gemm32_k(
    const float* __restrict__ A, int lda, const float* __restrict__ W, int ldw,
    const float* __restrict__ bias, float* __restrict__ C, int ldc, int K, int act)
{
  __shared__ float As[32 * 36];
  __shared__ float Ws[32 * 68];
  const int tid = threadIdx.x;
  const int m0 = blockIdx.y * 32, n0 = blockIdx.x * 64;
  const int tx = tid & 15, ty = tid >> 4;
  const int r0 = ty * 2, c0 = tx * 4;
  const int lr = tid >> 3, lk = (tid & 7) * 4;
  const float* Ap = A + (size_t)(m0 + lr) * lda + lk;
  const float* Wp0 = W + (size_t)(n0 + lr) * ldw + lk;
  const float* Wp1 = W + (size_t)(n0 + lr + 32) * ldw + lk;
  float acc[2][4] = {{0.f, 0.f, 0.f, 0.f}, {0.f, 0.f, 0.f, 0.f}};
  for (int k0 = 0; k0 < K; k0 += 32) {
    float4 av = *(const float4*)(Ap + k0);
    float4 w0 = *(const float4*)(Wp0 + k0);
    float4 w1 = *(const float4*)(Wp1 + k0);
    __syncthreads();
    As[(lk + 0) * 36 + lr] = av.x; As[(lk + 1) * 36 + lr] = av.y;
    As[(lk + 2) * 36 + lr] = av.z; As[(lk + 3) * 36 + lr] = av.w;
    Ws[(lk + 0) * 68 + lr] = w0.x; Ws[(lk + 1) * 68 + lr] = w0.y;
    Ws[(lk + 2) * 68 + lr] = w0.z; Ws[(lk + 3) * 68 + lr] = w0.w;
    Ws[(lk + 0) * 68 + lr + 32] = w1.x; Ws[(lk + 1) * 68 + lr + 32] = w1.y;
    Ws[(lk + 2) * 68 + lr + 32] = w1.z; Ws[(lk + 3) * 68 + lr + 32] = w1.w;
    __syncthreads();
#pragma unroll
    for (int kk = 0; kk < 32; ++kk) {
      float2 a = *(const float2*)&As[kk * 36 + r0];
      float4 w = *(const float4*)&Ws[kk * 68 + c0];
      const float aa[2] = {a.x, a.y};
      const float* wwp = (const float*)&w;
#pragma unroll
      for (int i = 0; i < 2; ++i)
#pragma unroll
        for (int j = 0; j < 4; ++j)
          acc[i][j] = fmaf(aa[i], wwp[j], acc[i][j]);
    }
  }
#pragma unroll
  for (int i = 0; i < 2; ++i)
#pragma unroll
    for (int j = 0; j < 4; ++j)
      C[(size_t)(m0 + r0 + i) * ldc + n0 + c0 + j] =
          actf(acc[i][j] + bias[n0 + c0 + j], act);
}

// h0 -> xAll slot 31 (bf16)
__global__ __launch_bounds__(256) void k_cvt_h0(
    const float* __restrict__ h0f, ushort* __restrict__ xAll)
{
  int idx = blockIdx.x * 256 + threadIdx.x;   // 65536
  int b = idx >> 9, j = idx & 511;
  xAll[((size_t)31 * 128 + b) * 1536 + 1024 + j] = f2bf(h0f[idx]);
}

// ---------------------------------------------------------------------------
extern "C" void kernel_launch(void* const* d_in, const int* in_sizes, int n_in,
                              void* d_out, int out_size, void* d_ws, size_t ws_size,
                              hipStream_t stream)
{
  const float* ann      = (const float*)d_in[0];
  const int*   captions = (const int*)d_in[1];
  const int*   lengths  = (const int*)d_in[2];
  const float* E_emb    = (const float*)d_in[3];
  const float* W_init_h = (const float*)d_in[4];
  const float* b_init_h = (const float*)d_in[5];
  const float* W_init_c = (const float*)d_in[6];
  const float* b_init_c = (const float*)d_in[7];
  const float* W_att_f  = (const float*)d_in[8];
  const float* b_att_f  = (const float*)d_in[9];
  const float* W_att_h  = (const float*)d_in[10];
  const float* b_att_h  = (const float*)d_in[11];
  const float* w_att_v  = (const float*)d_in[12];
  const float* b_att_v  = (const float*)d_in[13];  // unused (softmax invariant)
  const float* W_beta   = (const float*)d_in[14];
  const float* b_beta   = (const float*)d_in[15];
  const float* W_ih     = (const float*)d_in[16];
  const float* W_hh     = (const float*)d_in[17];
  const float* b_ih     = (const float*)d_in[18];
  const float* b_hh     = (const float*)d_in[19];
  const float* W_y      = (const float*)d_in[20];
  const float* W_h      = (const float*)d_in[21];
  const float* W_z      = (const float*)d_in[22];
  const float* W_out    = (const float*)d_in[23];
  const float* b_out    = (const float*)d_in[24];

  float* out        = (float*)d_out;
  float* out_logits = out;
  float* out_alpha  = out + 39680000ll;
  float* out_dec    = out + 40457728ll;

  char* p = (char*)d_ws;
  auto alloc_us = [&](size_t n) { ushort* r = (ushort*)p; p += ((n * 2 + 255) & ~(size_t)255); return r; };
  auto alloc_f  = [&](size_t n) { float*  r = (float*)p;  p += ((n * 4 + 255) & ~(size_t)255); return r; };
  ushort* Wo_bf    = alloc_us(10112 * 512);
  ushort* WgR_bf   = alloc_us(2048 * 1024);
  ushort* WgE_bf   = alloc_us(2048 * 512);
  ushort* Wcat2_bf = alloc_us(512 * 1536);
  ushort* Waf_bf   = alloc_us(512 * 512);
  ushort* Wah_bf   = alloc_us(512 * 512);
  ushort* Wb_bf    = alloc_us(512 * 512);
  ushort* ann_bf   = alloc_us(12845056);
  ushort* annp_bf  = alloc_us(12845056);
  ushort* preA_bf  = alloc_us(3968 * 512);
  ushort* xAll     = alloc_us(32 * 128 * 1536);
  ushort* embG     = alloc_us(3968 * 2048);
  float* biascR = alloc_f(2048);
  float* b_hf   = alloc_f(512);
  float* hpP    = alloc_f(4 * 65536);
  float* gpP    = alloc_f(4 * 65536);
  float* gP     = alloc_f(2 * 262144);
  float* cbuf   = alloc_f(65536);
  float* meanb  = alloc_f(65536);
  float* h0f    = alloc_f(65536);
  int*   declen = (int*)alloc_f(128);

  // ---- phase 1 ----
  hipLaunchKernelGGL(k_prep, dim3(1024), dim3(256), 0, stream,
                     W_ih, W_hh, b_ih, b_hh, W_y, W_h, W_z, W_out,
                     W_att_f, W_att_h, W_beta, b_att_f, b_att_h, ann,
                     captions, E_emb,
                     WgR_bf, WgE_bf, Wcat2_bf, Wo_bf, Waf_bf, Wah_bf, Wb_bf,
                     ann_bf, xAll, biascR, b_hf);
  hipLaunchKernelGGL(k_mean, dim3(128), dim3(256), 0, stream,
                     ann, lengths, meanb, declen, out_dec);
  hipLaunchKernelGGL(gemm32_k, dim3(8, 4), dim3(256), 0, stream,
                     meanb, 512, W_init_h, 512, b_init_h, h0f, 512, 512, 2);
  hipLaunchKernelGGL(gemm32_k, dim3(8, 4), dim3(256), 0, stream,
                     meanb, 512, W_init_c, 512, b_init_c, cbuf, 512, 512, 2);
  hipLaunchKernelGGL(k_cvt_h0, dim3(256), dim3(256), 0, stream, h0f, xAll);
  // annp = ann_bf @ Waf^T (bf16)
  hipLaunchKernelGGL(k_mfma, dim3(4, 196), dim3(256), 0, stream,
                     ann_bf, 512, Waf_bf, 512, 512, 1, (const float*)nullptr,
                     (float*)nullptr, annp_bf, 512);
  // embG = embAll @ WgE^T (bf16, 3968x2048)
  hipLaunchKernelGGL(k_mfma, dim3(16, 31), dim3(256), 0, stream,
                     xAll, 1536, WgE_bf, 512, 512, 1, (const float*)nullptr,
                     (float*)nullptr, embG, 2048);
  // init hp/gp from h0 (slot 31)
  hipLaunchKernelGGL(k_tail, dim3(32), dim3(256), 0, stream,
                     xAll, Wah_bf, Wb_bf, hpP, gpP, 31);

  // ---- phase 2: 31 steps ----
  for (int t = 0; t < 31; ++t) {
    int prev = (t == 0) ? 31 : t - 1;
    hipLaunchKernelGGL(k_attn, dim3(128), dim3(1024), 0, stream,
                       annp_bf, ann_bf, hpP, gpP, b_hf, b_beta,
                       w_att_v, declen, xAll, out_alpha, t);
    hipLaunchKernelGGL(k_gates, dim3(32), dim3(256), 0, stream,
                       xAll, WgR_bf, gP, t, prev);
    hipLaunchKernelGGL(k_lstm, dim3(256), dim3(256), 0, stream,
                       gP, embG, biascR, cbuf, declen, xAll, t, prev);
    hipLaunchKernelGGL(k_tail, dim3(32), dim3(256), 0, stream,
                       xAll, Wah_bf, Wb_bf, hpP, gpP, t);
  }

  // ---- phase 3: pre = tanh(xAll @ Wcat2^T); logits ----
  hipLaunchKernelGGL(k_mfma, dim3(4, 31), dim3(256), 0, stream,
                     xAll, 1536, Wcat2_bf, 1536, 1536, 2, (const float*)nullptr,
                     (float*)nullptr, preA_bf, 512);
  hipLaunchKernelGGL(k_logits, dim3(2480), dim3(256), 0, stream,
                     preA_bf, Wo_bf, b_out, out_logits, declen);
}